// Round 10
// baseline (308.801 us; speedup 1.0000x reference)
//
#include <hip/hip_runtime.h>

// WARP loss: B=4096 rows, Y=10000 labels, T=128 negative-candidate trials.
// input [B,Y] f32, target [B,Y] f32 (one-hot), neg_candidates [B,T] i32.
// out[0] = sum over rows of log((Y-1)/num_trials) * (1 - s_pos + s_neg),
// num_trials = 1 + first t with 1 + s_neg_t - s_pos >= 0 (0 contribution if none).
//
// Byte-minimal design (R0-R8 evidence: reads cap ~2.4 TB/s regardless of
// structure; time ~ fixed + bytes/BW, so minimize bytes and dispatches):
//   - one wave per row; 1 KB (1-group) scan chunks, ping-pong depth-2,
//     refill AFTER check -> overshoot <= ~2 KB; E[target read] ~ 22 KB/row
//   - non-temporal loads on the target stream (read-once, no cache pollute)
//   - stage-A = first 8 candidates (reject-all-8 prob ~1e-5); progressive
//     widening 8 -> 64 -> 56 preserves exact first-accept semantics
//   - single kernel dispatch: per-wave atomicAdd(out) (R0 baseline proved
//     arbitrary-order atomic sum passes, absmax 0.0); 4-byte memsetAsync
//     replaces the reduce dispatch (~5-8 us latency-bound block).

constexpr int Yc = 10000;
constexpr int Tc = 128;
constexpr int R4 = 2500;   // uint4 per row (40 KB, 16B-aligned per row)
constexpr int NG = 40;     // 1 KB groups per row (64 lanes x 16 B)

using u32x4 = unsigned int __attribute__((ext_vector_type(4)));

__global__ __launch_bounds__(256) void warp_fused_kernel(
        const float* __restrict__ input,
        const float* __restrict__ target,
        const int*   __restrict__ neg,
        float* __restrict__ out,
        int B) {
    const int wave = threadIdx.x >> 6;
    const int lane = threadIdx.x & 63;
    const int row  = blockIdx.x * 4 + wave;
    if (row >= B) return;                      // no barriers below: safe

    const int*   nrow = neg + row * Tc;
    const float* irow = input + (size_t)row * Yc;
    const u32x4* trow = reinterpret_cast<const u32x4*>(target + (size_t)row * Yc);

    auto LDG = [&](int g) -> u32x4 {           // group g, lane's 16 B, NT load
        int idx = g * 64 + lane;
        if (idx >= R4) idx = R4 - 1;           // clamp: duplicate last element
        return __builtin_nontemporal_load(&trow[idx]);
    };
    // min one-hot element index within one group, or -1 (wave-uniform)
    auto CHK = [&](int g, const u32x4& v) -> int {
        const unsigned nz = v[0] | v[1] | v[2] | v[3];
        if (!__any(nz != 0)) return -1;
        int mine = 0x7fffffff;
        if (nz) {
            int idx = g * 64 + lane; if (idx >= R4) idx = R4 - 1;
            int sub = v[0] ? 0 : (v[1] ? 1 : (v[2] ? 2 : 3));
            mine = 4 * idx + sub;
        }
        #pragma unroll
        for (int off = 32; off; off >>= 1)
            mine = min(mine, __shfl_xor(mine, off));
        return mine;
    };

    // ---- prologue: stage-A neg (1 line) + 8 gather lines fly under scan ----
    const int cA = nrow[lane & 7];             // trials 0..7 (x8 dup)
    u32x4 A = LDG(0), Bv = LDG(1);
    const float sA = irow[cA];                 // waits only on cA; A,Bv in flight

    // ---- early-exit scan, 1 KB ping-pong, refill after check ----
    int posIdx = -1;
    for (int g = 0; g < NG; g += 2) {
        posIdx = CHK(g, A);                    // waits A only
        if (posIdx >= 0) break;
        if (g + 2 < NG) A = LDG(g + 2);
        posIdx = CHK(g + 1, Bv);               // waits Bv only
        if (posIdx >= 0) break;
        if (g + 3 < NG) Bv = LDG(g + 3);
    }

    const float s_pos = (posIdx >= 0) ? irow[posIdx] : 0.0f;  // 1 line, bcast

    // ---- progressive first-accept: 8 -> 64 -> 56 trials ----
    int   first = -1;
    float s_neg = 0.0f;
    const unsigned long long bA =
        __ballot(1.0f + sA - s_pos >= 0.0f) & 0xFFull;        // trials 0..7
    if (bA) {
        first = __ffsll(bA) - 1;
        s_neg = __shfl(sA, first);
    } else {
        const int   cB = nrow[8 + lane];                      // trials 8..71
        const float sB = irow[cB];
        const unsigned long long bB = __ballot(1.0f + sB - s_pos >= 0.0f);
        if (bB) {
            const int f = __ffsll(bB) - 1;
            first = 8 + f;
            s_neg = __shfl(sB, f);
        } else {
            const int   iC = 72 + lane;                       // trials 72..127
            const int   cC = nrow[iC < Tc ? iC : Tc - 1];
            const float sC = irow[cC];
            const unsigned long long bC =
                __ballot(1.0f + sC - s_pos >= 0.0f) & ((1ull << 56) - 1);
            if (bC) {
                const int f = __ffsll(bC) - 1;
                first = 72 + f;
                s_neg = __shfl(sC, f);
            }
        }
    }

    if (lane == 0 && posIdx >= 0 && first >= 0) {
        const int   nt = first + 1;
        const float L  = logf((float)((Yc - 1) / nt));        // floor-div, log
        atomicAdd(out, L * (1.0f - s_pos + s_neg));
    }
}

extern "C" void kernel_launch(void* const* d_in, const int* in_sizes, int n_in,
                              void* d_out, int out_size, void* d_ws, size_t ws_size,
                              hipStream_t stream) {
    const float* input  = (const float*)d_in[0];
    const float* target = (const float*)d_in[1];
    const int*   neg    = (const int*)d_in[2];
    float* out = (float*)d_out;

    const int B    = in_sizes[2] / Tc;         // 4096
    const int nblk = (B + 3) / 4;              // 1024 blocks, 1 wave per row

    // Harness re-poisons d_out before every replay: zero it (graph-safe).
    hipMemsetAsync(out, 0, sizeof(float), stream);
    warp_fused_kernel<<<nblk, 256, 0, stream>>>(input, target, neg, out, B);
}

// Round 11
// 280.995 us; speedup vs baseline: 1.0990x; 1.0990x over previous
//
#include <hip/hip_runtime.h>

// WARP loss: B=4096 rows, Y=10000 labels, T=128 negative-candidate trials.
// input [B,Y] f32, target [B,Y] f32 (one-hot), neg_candidates [B,T] i32.
// out[0] = sum over rows of log((Y-1)/num_trials) * (1 - s_pos + s_neg),
// num_trials = 1 + first t with 1 + s_neg_t - s_pos >= 0 (0 contribution if none).
//
// Byte-minimal design (R0-R10 evidence: reads cap ~2.4 TB/s regardless of
// structure; time ~ fixed + bytes/BW, so minimize bytes):
//   - one wave per row; 1 KB (1-group) scan chunks, ping-pong depth-2,
//     refill AFTER check -> overshoot <= ~2 KB; E[target read] ~ 22 KB/row
//   - non-temporal loads on the target stream (read-once, no cache pollute)
//   - stage-A = first 8 candidates (reject-all-8 prob ~1e-5); progressive
//     widening 8 -> 64 -> 56 preserves exact first-accept semantics
//   - per-row partials in d_ws; 1-block reduce writes out[0] (overwrites
//     harness poison; no memset, no global atomics). R10 measured that
//     replacing this with 4096 same-address device atomics costs +30 us
//     (coherence-point serialization) -- keep the two-dispatch reduce.

constexpr int Yc = 10000;
constexpr int Tc = 128;
constexpr int R4 = 2500;   // uint4 per row (40 KB, 16B-aligned per row)
constexpr int NG = 40;     // 1 KB groups per row (64 lanes x 16 B)

using u32x4 = unsigned int __attribute__((ext_vector_type(4)));

__global__ __launch_bounds__(256) void warp_fused_kernel(
        const float* __restrict__ input,
        const float* __restrict__ target,
        const int*   __restrict__ neg,
        float* __restrict__ partial,
        int B) {
    const int wave = threadIdx.x >> 6;
    const int lane = threadIdx.x & 63;
    const int row  = blockIdx.x * 4 + wave;
    if (row >= B) return;                      // no barriers below: safe

    const int*   nrow = neg + row * Tc;
    const float* irow = input + (size_t)row * Yc;
    const u32x4* trow = reinterpret_cast<const u32x4*>(target + (size_t)row * Yc);

    auto LDG = [&](int g) -> u32x4 {           // group g, lane's 16 B, NT load
        int idx = g * 64 + lane;
        if (idx >= R4) idx = R4 - 1;           // clamp: duplicate last element
        return __builtin_nontemporal_load(&trow[idx]);
    };
    // min one-hot element index within one group, or -1 (wave-uniform)
    auto CHK = [&](int g, const u32x4& v) -> int {
        const unsigned nz = v[0] | v[1] | v[2] | v[3];
        if (!__any(nz != 0)) return -1;
        int mine = 0x7fffffff;
        if (nz) {
            int idx = g * 64 + lane; if (idx >= R4) idx = R4 - 1;
            int sub = v[0] ? 0 : (v[1] ? 1 : (v[2] ? 2 : 3));
            mine = 4 * idx + sub;
        }
        #pragma unroll
        for (int off = 32; off; off >>= 1)
            mine = min(mine, __shfl_xor(mine, off));
        return mine;
    };

    // ---- prologue: stage-A neg (1 line) + 8 gather lines fly under scan ----
    const int cA = nrow[lane & 7];             // trials 0..7 (x8 dup)
    u32x4 A = LDG(0), Bv = LDG(1);
    const float sA = irow[cA];                 // waits only on cA; A,Bv in flight

    // ---- early-exit scan, 1 KB ping-pong, refill after check ----
    int posIdx = -1;
    for (int g = 0; g < NG; g += 2) {
        posIdx = CHK(g, A);                    // waits A only
        if (posIdx >= 0) break;
        if (g + 2 < NG) A = LDG(g + 2);
        posIdx = CHK(g + 1, Bv);               // waits Bv only
        if (posIdx >= 0) break;
        if (g + 3 < NG) Bv = LDG(g + 3);
    }

    const float s_pos = (posIdx >= 0) ? irow[posIdx] : 0.0f;  // 1 line, bcast

    // ---- progressive first-accept: 8 -> 64 -> 56 trials ----
    int   first = -1;
    float s_neg = 0.0f;
    const unsigned long long bA =
        __ballot(1.0f + sA - s_pos >= 0.0f) & 0xFFull;        // trials 0..7
    if (bA) {
        first = __ffsll(bA) - 1;
        s_neg = __shfl(sA, first);
    } else {
        const int   cB = nrow[8 + lane];                      // trials 8..71
        const float sB = irow[cB];
        const unsigned long long bB = __ballot(1.0f + sB - s_pos >= 0.0f);
        if (bB) {
            const int f = __ffsll(bB) - 1;
            first = 8 + f;
            s_neg = __shfl(sB, f);
        } else {
            const int   iC = 72 + lane;                       // trials 72..127
            const int   cC = nrow[iC < Tc ? iC : Tc - 1];
            const float sC = irow[cC];
            const unsigned long long bC =
                __ballot(1.0f + sC - s_pos >= 0.0f) & ((1ull << 56) - 1);
            if (bC) {
                const int f = __ffsll(bC) - 1;
                first = 72 + f;
                s_neg = __shfl(sC, f);
            }
        }
    }

    float contrib = 0.0f;
    if (posIdx >= 0 && first >= 0) {
        const int   nt = first + 1;
        const float L  = logf((float)((Yc - 1) / nt));        // floor-div, log
        contrib = L * (1.0f - s_pos + s_neg);
    }
    if (lane == 0) partial[row] = contrib;
}

__global__ __launch_bounds__(256) void reduce_partials(
        const float* __restrict__ partial,
        float* __restrict__ out, int n) {
    float s = 0.0f;
    for (int i = threadIdx.x; i < n; i += 256) s += partial[i];
    #pragma unroll
    for (int off = 32; off; off >>= 1) s += __shfl_down(s, off);
    __shared__ float ws[4];
    if ((threadIdx.x & 63) == 0) ws[threadIdx.x >> 6] = s;
    __syncthreads();
    if (threadIdx.x == 0) out[0] = ws[0] + ws[1] + ws[2] + ws[3];
}

extern "C" void kernel_launch(void* const* d_in, const int* in_sizes, int n_in,
                              void* d_out, int out_size, void* d_ws, size_t ws_size,
                              hipStream_t stream) {
    const float* input  = (const float*)d_in[0];
    const float* target = (const float*)d_in[1];
    const int*   neg    = (const int*)d_in[2];
    float* out     = (float*)d_out;
    float* partial = (float*)d_ws;             // B floats

    const int B    = in_sizes[2] / Tc;         // 4096
    const int nblk = (B + 3) / 4;              // 1024 blocks, 1 wave per row

    warp_fused_kernel<<<nblk, 256, 0, stream>>>(input, target, neg, partial, B);
    reduce_partials<<<1, 256, 0, stream>>>(partial, out, B);
}